// Round 1
// baseline (44.930 us; speedup 1.0000x reference)
//
#include <hip/hip_runtime.h>

// GAE: A_t = delta_t + (gamma*lam) * A_{t+1}, backward over S; returns = A + values.
// Constant-coefficient linear recurrence -> exact parallel weighted suffix scan.

#define GAMMA 0.99f
#define LAM   0.95f

constexpr int S_LEN = 4096;
constexpr int TPB   = 256;
constexpr int CHUNK = S_LEN / TPB; // 16 elements per thread

__global__ __launch_bounds__(TPB) void gae_kernel(const float* __restrict__ rewards,
                                                  const float* __restrict__ values,
                                                  const float* __restrict__ next_values,
                                                  float* __restrict__ out, int B) {
    __shared__ float vals[S_LEN];
    __shared__ float rews[S_LEN];   // reused later to stage advantages for coalesced store
    __shared__ float waveT[4];

    const int b   = blockIdx.x;
    const int tid = threadIdx.x;
    const float c = GAMMA * LAM;

    const float* vrow = values  + (size_t)b * S_LEN;
    const float* rrow = rewards + (size_t)b * S_LEN;

    // ---- coalesced stage of both rows into LDS (float4) ----
#pragma unroll
    for (int j = 0; j < CHUNK / 4; ++j) {
        int idx = j * TPB + tid;
        ((float4*)vals)[idx] = ((const float4*)vrow)[idx];
        ((float4*)rews)[idx] = ((const float4*)rrow)[idx];
    }
    const float nv = next_values[b];
    __syncthreads();

    // ---- per-thread local backward scan over its 16-element chunk ----
    const int base = tid * CHUNK;
    float a[CHUNK];
    float acc = 0.f;
#pragma unroll
    for (int li = CHUNK - 1; li >= 0; --li) {
        int i = base + li;
        float vnext = (i == S_LEN - 1) ? nv : vals[i + 1];
        float delta = rews[i] + GAMMA * vnext - vals[i];
        acc = delta + c * acc;
        a[li] = acc;
    }
    float v = acc; // chunk value: A at chunk start assuming zero incoming carry

    // q = c^CHUNK
    float q = 1.f;
#pragma unroll
    for (int k = 0; k < CHUNK; ++k) q *= c;

    // ---- intra-wave weighted suffix scan (64 lanes, factor q) ----
    const int lane = tid & 63;
    const int wave = tid >> 6;
    float x = v;
    float qs[6];      // q^(2^k) saved for binary exponentiation later
    float qd = q;
#pragma unroll
    for (int dlog = 0; dlog < 6; ++dlog) {
        int d = 1 << dlog;
        qs[dlog] = qd;
        float other = __shfl_down(x, d);
        if (lane + d < 64) x += qd * other;
        qd *= qd;       // q^d -> q^(2d)
    }
    const float Q = qd; // q^64

    // ---- cross-wave combine: wave totals -> carries ----
    if (lane == 0) waveT[wave] = x;
    __syncthreads();
    float t0 = waveT[0], t1 = waveT[1], t2 = waveT[2], t3 = waveT[3];
    (void)t0;
    float F3 = t3;
    float F2 = t2 + Q * F3;
    float F1 = t1 + Q * F2;
    // carry entering wave w (i.e., A at start of wave w+1), F4 = 0
    float carry_wave = (wave == 3) ? 0.f : (wave == 2 ? F3 : (wave == 1 ? F2 : F1));

    // C_t = A at start of chunk t+1 = W[lane+1] + q^(63-lane) * carry_wave
    float Wnext = __shfl_down(x, 1);
    int e = 63 - lane;
    float qp = 1.f;
#pragma unroll
    for (int k = 0; k < 6; ++k) qp *= ((e >> k) & 1) ? qs[k] : 1.f;
    float C = (lane == 63) ? carry_wave : fmaf(qp, carry_wave, Wnext);

    // ---- apply carry into local chunk: A[li] += c^(16-li) * C ----
    float p = c;
#pragma unroll
    for (int li = CHUNK - 1; li >= 0; --li) {
        a[li] = fmaf(p, C, a[li]);
        p *= c;
    }

    // ---- stage advantages into LDS (rews is dead) for coalesced stores ----
    __syncthreads(); // all rews reads finished before waveT barrier; this orders the overwrite vs stores
#pragma unroll
    for (int li = 0; li < CHUNK; ++li) rews[base + li] = a[li];
    __syncthreads();

    float* adv_row = out + (size_t)b * S_LEN;
    float* ret_row = out + (size_t)B * S_LEN + (size_t)b * S_LEN;
#pragma unroll
    for (int j = 0; j < CHUNK / 4; ++j) {
        int idx = j * TPB + tid;
        float4 av = ((float4*)rews)[idx];
        float4 vv = ((float4*)vals)[idx];
        float4 rv = make_float4(av.x + vv.x, av.y + vv.y, av.z + vv.z, av.w + vv.w);
        ((float4*)adv_row)[idx] = av;
        ((float4*)ret_row)[idx] = rv;
    }
}

extern "C" void kernel_launch(void* const* d_in, const int* in_sizes, int n_in,
                              void* d_out, int out_size, void* d_ws, size_t ws_size,
                              hipStream_t stream) {
    const float* rewards     = (const float*)d_in[0];
    const float* values      = (const float*)d_in[1];
    const float* next_values = (const float*)d_in[2];
    float* out = (float*)d_out;
    const int B = in_sizes[2];             // 4096
    // S fixed at 4096 by the reference harness (in_sizes[0] == B * 4096)
    gae_kernel<<<B, TPB, 0, stream>>>(rewards, values, next_values, out, B);
}